// Round 3
// baseline (789.786 us; speedup 1.0000x reference)
//
#include <hip/hip_runtime.h>
#include <math.h>

// RoutingLayer fused: routing = x@w_gate + noise*(softplus(x@w_noise)+0.01);
// out = scatter(softmax(top2(routing)))
// x: 32768x2048 fp32, w_gate/w_noise: 2048x64, noise: 32768x64, out: 32768x64.
//
// R3: LDS-free K-loop. R2 was LDS-pipe-bound (288 LDS-cyc vs 128 VALU-cyc per
// CU per k). New decomposition: wave = 64 rows x 16 experts (gate+noise).
//  - B operand: column base made uniform via readfirstlane -> compiler emits
//    s_load_dwordx16; FMA reads B from SGPRs (free operand). No LDS, no VGPRs.
//  - A operand: lane=row, per-thread float4 of x every 4 k. Same 64-B line
//    reused 4x in-thread; 4 waves/block share rows (~512 lines = L1).
//  - 32 fp32 acc/thread, 65536 FMAs, no barriers in the main loop.
// Epilogue: per-thread top-2 of its 16 experts, 4-way merge in 5 KB LDS,
// coalesced 64-wide row writes (4 lanes per row).

constexpr int DIMK = 2048;
constexpr int NEXP = 64;
constexpr int ROWS_PER_BLOCK = 64;
constexpr int NTHREADS = 256;          // 4 waves = 4 expert groups of 16

__device__ __forceinline__ bool gt_pair(float a, int ia, float b, int ib) {
    // "a beats b" with jax top_k tie-break (lower index wins on equal value)
    return (a > b) || (a == b && ia < ib);
}

__global__ __launch_bounds__(NTHREADS)
void routing_kernel(const float* __restrict__ x,
                    const float* __restrict__ wg,
                    const float* __restrict__ wn,
                    const float* __restrict__ noise,
                    float* __restrict__ out)
{
    __shared__ float4 cand[ROWS_PER_BLOCK][4];   // per-wave top2 candidates
    __shared__ float4 res[ROWS_PER_BLOCK];       // merged {g1,i1,g2,i2}

    const int tid  = threadIdx.x;
    const int lane = tid & 63;
    const int w    = tid >> 6;                   // wave id = expert group
    // uniform column base -> B loads become s_load (SGPR operands)
    const int cb   = __builtin_amdgcn_readfirstlane(w * 16);
    const int row0 = blockIdx.x * ROWS_PER_BLOCK;
    const int row  = row0 + lane;

    const float* __restrict__ xr = x  + (size_t)row * DIMK;
    const float* __restrict__ bg = wg + cb;      // bg[k*NEXP + e], uniform addr
    const float* __restrict__ bn = wn + cb;

    float ag[16] = {};
    float an[16] = {};

    // main K-loop: 4 k per iter, A prefetched 2 quads ahead
    float4 abuf0 = *reinterpret_cast<const float4*>(xr + 0);
    float4 abuf1 = *reinterpret_cast<const float4*>(xr + 4);
    for (int k0 = 0; k0 < DIMK; k0 += 4) {
        const float4 acur = abuf0;
        abuf0 = abuf1;
        if (k0 + 8 < DIMK)
            abuf1 = *reinterpret_cast<const float4*>(xr + k0 + 8);
        const float av[4] = {acur.x, acur.y, acur.z, acur.w};
        #pragma unroll
        for (int j = 0; j < 4; ++j) {
            const size_t kb = (size_t)(k0 + j) * NEXP;
            #pragma unroll
            for (int e = 0; e < 16; ++e) {
                ag[e] = fmaf(av[j], bg[kb + e], ag[e]);
                an[e] = fmaf(av[j], bn[kb + e], an[e]);
            }
        }
    }

    // ---- epilogue ----
    // routing values for this thread's 16 experts
    const float* nzp = noise + (size_t)row * NEXP + cb;
    float nzv[16];
    #pragma unroll
    for (int q = 0; q < 4; ++q) {
        float4 nz = *reinterpret_cast<const float4*>(nzp + q * 4);
        nzv[q * 4 + 0] = nz.x; nzv[q * 4 + 1] = nz.y;
        nzv[q * 4 + 2] = nz.z; nzv[q * 4 + 3] = nz.w;
    }
    float v1 = -INFINITY, v2 = -INFINITY;
    int i1 = 0, i2 = 0;
    #pragma unroll
    for (int e = 0; e < 16; ++e) {
        float v  = an[e];
        float sp = fmaxf(v, 0.f) + log1pf(expf(-fabsf(v)));
        float r  = ag[e] + nzv[e] * (sp + 0.01f);
        int   ge = cb + e;
        if (r > v1)      { v2 = v1; i2 = i1; v1 = r; i1 = ge; }
        else if (r > v2) { v2 = r; i2 = ge; }
    }
    cand[lane][w] = make_float4(v1, __int_as_float(i1), v2, __int_as_float(i2));
    __syncthreads();

    // one thread per row merges the 4 wave-candidates
    if (tid < ROWS_PER_BLOCK) {
        float4 c0 = cand[tid][0];
        float mv1 = c0.x; int mi1 = __float_as_int(c0.y);
        float mv2 = c0.z; int mi2 = __float_as_int(c0.w);
        #pragma unroll
        for (int g = 1; g < 4; ++g) {
            float4 c = cand[tid][g];
            float b1 = c.x; int ib1 = __float_as_int(c.y);
            float b2 = c.z; int ib2 = __float_as_int(c.w);
            if (gt_pair(b1, ib1, mv1, mi1)) {
                float o1 = mv1; int oi1 = mi1;
                mv1 = b1; mi1 = ib1;
                if (gt_pair(b2, ib2, o1, oi1)) { mv2 = b2; mi2 = ib2; }
                else                           { mv2 = o1; mi2 = oi1; }
            } else if (gt_pair(b1, ib1, mv2, mi2)) {
                mv2 = b1; mi2 = ib1;
            }
        }
        float t  = expf(mv2 - mv1);      // <= 1, no overflow
        float g1 = 1.f / (1.f + t);
        res[tid] = make_float4(g1, __int_as_float(mi1),
                               t * g1, __int_as_float(mi2));
    }
    __syncthreads();

    // coalesced scatter: 4 consecutive lanes write one 64-float row
    {
        const int rr  = tid >> 2;           // row within block
        const int seg = tid & 3;            // 16-col segment
        float4 rv = res[rr];
        float g1 = rv.x, g2 = rv.z;
        int   j1 = __float_as_int(rv.y), j2 = __float_as_int(rv.w);
        float* op = out + (size_t)(row0 + rr) * NEXP + seg * 16;
        #pragma unroll
        for (int q = 0; q < 4; ++q) {
            int e0 = seg * 16 + q * 4;
            float4 o;
            o.x = (e0 + 0 == j1) ? g1 : ((e0 + 0 == j2) ? g2 : 0.f);
            o.y = (e0 + 1 == j1) ? g1 : ((e0 + 1 == j2) ? g2 : 0.f);
            o.z = (e0 + 2 == j1) ? g1 : ((e0 + 2 == j2) ? g2 : 0.f);
            o.w = (e0 + 3 == j1) ? g1 : ((e0 + 3 == j2) ? g2 : 0.f);
            *reinterpret_cast<float4*>(op + q * 4) = o;
        }
    }
}

extern "C" void kernel_launch(void* const* d_in, const int* in_sizes, int n_in,
                              void* d_out, int out_size, void* d_ws, size_t ws_size,
                              hipStream_t stream) {
    const float* x     = (const float*)d_in[0];
    const float* wg    = (const float*)d_in[1];
    const float* wn    = (const float*)d_in[2];
    const float* noise = (const float*)d_in[3];
    float* out = (float*)d_out;

    const int Brows = in_sizes[0] / DIMK;              // 32768
    dim3 grid(Brows / ROWS_PER_BLOCK);                 // 512 blocks
    routing_kernel<<<grid, NTHREADS, 0, stream>>>(x, wg, wn, noise, out);
}

// Round 4
// 422.307 us; speedup vs baseline: 1.8702x; 1.8702x over previous
//
#include <hip/hip_runtime.h>
#include <math.h>

// RoutingLayer fused via split-fp16 MFMA emulation of fp32 GEMM.
// routing = x@w_gate + noise*(softplus(x@w_noise)+0.01); out = scatter(softmax(top2)).
// x: 32768x2048 fp32, w_*: 2048x64 fp32, noise: 32768x64, out: 32768x64.
//
// R4: x' = 1024*x = x1+x2 (fp16), w' = 65536*w = w1+w2 (fp16, pre-split into
// B-frag order in d_ws by a pre-kernel). acc += x1w1 + x1w2 + x2w1 via
// mfma_f32_16x16x32_f16 (dropped x2w2 ~2^-22 => dot err ~5e-8 < fp32 noise).
// Scale factors keep all fp16 operands in normal range (no denorm-flush risk).
// Memory-bound target: read x once (268 MB) => ~45 us HBM floor.

typedef _Float16 half4v __attribute__((ext_vector_type(4)));
typedef _Float16 half8v __attribute__((ext_vector_type(8)));
typedef float f32x4 __attribute__((ext_vector_type(4)));

constexpr int DIMK = 2048;
constexpr int NEXP = 64;
constexpr int BM   = 64;     // rows per block
constexpr int NCH  = DIMK / 32;  // 64 k-chunks of 32

__device__ __forceinline__ void async_load16(const void* g, void* l) {
    // global -> LDS DMA, 16B/lane; LDS dest = uniform base + lane*16
    __builtin_amdgcn_global_load_lds(
        (const __attribute__((address_space(1))) unsigned int*)g,
        (__attribute__((address_space(3))) unsigned int*)l, 16, 0, 0);
}

__device__ __forceinline__ bool gt_pair(float a, int ia, float b, int ib) {
    return (a > b) || (a == b && ia < ib);   // jax top_k: lower index wins ties
}

// ---- pre-kernel: split w' = 65536*[wg|wn] into 2 fp16 planes in B-frag order.
// ws layout: [chunk c][plane p][ntile t][lane][8 halfs]  (1KB per (c,p,t))
// B-frag (16x16x32): lane holds B[k = c*32 + (lane>>4)*8 + j][n = t*16 + (lane&15)]
__global__ __launch_bounds__(256)
void presplit_kernel(const float* __restrict__ wg, const float* __restrict__ wn,
                     _Float16* __restrict__ wsB)
{
    int gid  = blockIdx.x * 256 + threadIdx.x;   // 0..32767 = (c, t, lane)
    int lane = gid & 63;
    int t    = (gid >> 6) & 7;
    int c    = gid >> 9;
    int n    = t * 16 + (lane & 15);
    int kb   = c * 32 + ((lane >> 4) << 3);
    const float* src = (n < NEXP) ? (wg + n) : (wn + (n - NEXP));
    half8v h1, h2;
    #pragma unroll
    for (int j = 0; j < 8; ++j) {
        float w = src[(size_t)(kb + j) * NEXP] * 65536.0f;
        _Float16 a = (_Float16)w;
        h1[j] = a;
        h2[j] = (_Float16)(w - (float)a);
    }
    *(half8v*)(wsB + ((((size_t)c * 2 + 0) * 8 + t) * 64 + lane) * 8) = h1;
    *(half8v*)(wsB + ((((size_t)c * 2 + 1) * 8 + t) * 64 + lane) * 8) = h2;
}

// ---- main kernel: 256 threads = 4 waves as (wm = row-half, wn = expert-half).
// Wave tile: 32 rows x [16+16 gate cols | matching 16+16 noise cols].
__global__ __launch_bounds__(256)
void routing_mfma(const float* __restrict__ x, const _Float16* __restrict__ wsB,
                  const float* __restrict__ noise, float* __restrict__ out)
{
    __shared__ float    Xs[2][BM][32];            // 16 KB  (x fp32, dbuf)
    __shared__ _Float16 Bp[2][2][8][64][8];       // 32 KB  (B planes, dbuf)
    __shared__ _Float16 Ap[2][4][64][8];          // 8 KB   (A planes, single)
    __shared__ float4   cand[BM][2];              // 2 KB
    __shared__ float4   res[BM];                  // 1 KB

    const int tid  = threadIdx.x;
    const int lane = tid & 63;
    const int w    = tid >> 6;
    const int wm   = w >> 1;            // row half (0,1)
    const int wnh  = w & 1;             // expert half (0,1)
    const int q    = lane >> 4;
    const int cidx = lane & 15;
    const int row0 = blockIdx.x * BM;

    f32x4 acc[2][4] = {};               // [mt][tt: 0,1=gate tiles, 2,3=noise tiles]

    auto issue_loads = [&](int c, int buf) {
        #pragma unroll
        for (int ii = 0; ii < 2; ++ii) {          // x: 8 rows per instr, 128B bursts
            int i = w * 2 + ii;
            const float* g = x + (size_t)(row0 + i * 8 + (lane >> 3)) * DIMK
                               + c * 32 + (lane & 7) * 4;
            async_load16(g, &Xs[buf][i * 8][0]);
        }
        #pragma unroll
        for (int ii = 0; ii < 4; ++ii) {          // B: 1KB frag blocks from ws
            int idx = w * 4 + ii;
            int p = idx >> 3, t = idx & 7;
            const _Float16* g = wsB + ((((size_t)c * 2 + p) * 8 + t) * 64 + lane) * 8;
            async_load16(g, &Bp[buf][p][t][0][0]);
        }
    };

    issue_loads(0, 0);

    for (int c = 0; c < NCH; ++c) {
        const int cur = c & 1;
        __syncthreads();                          // drains vmcnt: Xs/Bp[cur] ready
        if (c + 1 < NCH) issue_loads(c + 1, cur ^ 1);

        // convert Xs[cur] -> A planes (frag-linear: [plane][mtile][lane'][j])
        #pragma unroll
        for (int it = 0; it < 2; ++it) {
            int fidx = it * 1024 + tid * 4;       // lane-contiguous b128 reads
            int row  = fidx >> 5;
            int kk0  = fidx & 31;
            const float4 v = *(const float4*)(&Xs[cur][0][0] + fidx);
            float f0 = v.x * 1024.f, f1 = v.y * 1024.f;
            float f2 = v.z * 1024.f, f3 = v.w * 1024.f;
            half4v h1, h2;
            h1[0] = (_Float16)f0; h2[0] = (_Float16)(f0 - (float)h1[0]);
            h1[1] = (_Float16)f1; h2[1] = (_Float16)(f1 - (float)h1[1]);
            h1[2] = (_Float16)f2; h2[2] = (_Float16)(f2 - (float)h1[2]);
            h1[3] = (_Float16)f3; h2[3] = (_Float16)(f3 - (float)h1[3]);
            int mtile = row >> 4;
            int lp    = (row & 15) + ((kk0 >> 3) << 4);   // frag lane'
            int j0    = kk0 & 7;
            *(half4v*)&Ap[0][mtile][lp][j0] = h1;
            *(half4v*)&Ap[1][mtile][lp][j0] = h2;
        }
        // LDS-only barrier: do NOT drain vmcnt (keeps c+1 loads in flight)
        asm volatile("s_waitcnt lgkmcnt(0)\n\ts_barrier" ::: "memory");

        // fragment reads (conflict-free b128: lane-linear 16B)
        half8v af[2][2], bf[4][2];
        #pragma unroll
        for (int mt = 0; mt < 2; ++mt)
            #pragma unroll
            for (int p = 0; p < 2; ++p)
                af[mt][p] = *(const half8v*)&Ap[p][wm * 2 + mt][lane][0];
        #pragma unroll
        for (int tt = 0; tt < 4; ++tt) {
            int ntile = (tt < 2) ? (wnh * 2 + tt) : (4 + wnh * 2 + (tt - 2));
            #pragma unroll
            for (int p = 0; p < 2; ++p)
                bf[tt][p] = *(const half8v*)&Bp[cur][p][ntile][lane][0];
        }
        // 3-pass split MFMA: x1w1 + x1w2 + x2w1
        #pragma unroll
        for (int mt = 0; mt < 2; ++mt)
            #pragma unroll
            for (int tt = 0; tt < 4; ++tt) {
                acc[mt][tt] = __builtin_amdgcn_mfma_f32_16x16x32_f16(
                    af[mt][0], bf[tt][0], acc[mt][tt], 0, 0, 0);
                acc[mt][tt] = __builtin_amdgcn_mfma_f32_16x16x32_f16(
                    af[mt][0], bf[tt][1], acc[mt][tt], 0, 0, 0);
                acc[mt][tt] = __builtin_amdgcn_mfma_f32_16x16x32_f16(
                    af[mt][1], bf[tt][0], acc[mt][tt], 0, 0, 0);
            }
    }

    // ---- epilogue ----
    // C/D layout: col = lane&15, row = q*4 + reg. Unscale by 2^-26 (1024*65536).
    const float s = 0x1p-26f;
    #pragma unroll
    for (int mt = 0; mt < 2; ++mt) {
        float rv[2][4];
        #pragma unroll
        for (int g = 0; g < 2; ++g) {
            int e     = wnh * 32 + g * 16 + cidx;
            int rbase = row0 + wm * 32 + mt * 16 + q * 4;
            #pragma unroll
            for (int r = 0; r < 4; ++r) {
                float nz   = noise[(size_t)(rbase + r) * NEXP + e];
                float gate = acc[mt][g][r] * s;
                float nv   = acc[mt][g + 2][r] * s;
                float sp   = fmaxf(nv, 0.f) + log1pf(expf(-fabsf(nv)));
                rv[g][r]   = gate + nz * (sp + 0.01f);
            }
        }
        #pragma unroll
        for (int r = 0; r < 4; ++r) {
            int e0 = wnh * 32 + cidx, e1 = e0 + 16;
            float v1, v2; int i1, i2;
            float a = rv[0][r], b = rv[1][r];
            if (a >= b) { v1 = a; i1 = e0; v2 = b; i2 = e1; }   // e0<e1: tie ok
            else        { v1 = b; i1 = e1; v2 = a; i2 = e0; }
            #pragma unroll
            for (int m = 1; m <= 8; m <<= 1) {    // butterfly across the 16-lane quad
                float b1 = __shfl_xor(v1, m); int ib1 = __shfl_xor(i1, m);
                float b2 = __shfl_xor(v2, m); int ib2 = __shfl_xor(i2, m);
                if (gt_pair(b1, ib1, v1, i1)) {
                    float o1 = v1; int oi1 = i1;
                    v1 = b1; i1 = ib1;
                    if (gt_pair(b2, ib2, o1, oi1)) { v2 = b2; i2 = ib2; }
                    else                           { v2 = o1; i2 = oi1; }
                } else if (gt_pair(b1, ib1, v2, i2)) {
                    v2 = b1; i2 = ib1;
                }
            }
            if (cidx == 0) {
                int rowb = wm * 32 + mt * 16 + q * 4 + r;
                cand[rowb][wnh] = make_float4(v1, __int_as_float(i1),
                                              v2, __int_as_float(i2));
            }
        }
    }
    __syncthreads();

    if (tid < BM) {   // merge the two expert-half candidates, softmax
        float4 c0 = cand[tid][0], c1 = cand[tid][1];
        float mv1 = c0.x; int mi1 = __float_as_int(c0.y);
        float mv2 = c0.z; int mi2 = __float_as_int(c0.w);
        float b1 = c1.x;  int ib1 = __float_as_int(c1.y);
        float b2 = c1.z;  int ib2 = __float_as_int(c1.w);
        if (gt_pair(b1, ib1, mv1, mi1)) {
            float o1 = mv1; int oi1 = mi1;
            mv1 = b1; mi1 = ib1;
            if (gt_pair(b2, ib2, o1, oi1)) { mv2 = b2; mi2 = ib2; }
            else                           { mv2 = o1; mi2 = oi1; }
        } else if (gt_pair(b1, ib1, mv2, mi2)) {
            mv2 = b1; mi2 = ib1;
        }
        float t  = expf(mv2 - mv1);     // <= 1
        float g1 = 1.f / (1.f + t);
        res[tid] = make_float4(g1, __int_as_float(mi1),
                               t * g1, __int_as_float(mi2));
    }
    __syncthreads();

    {   // write full 64x64 out tile: thread -> row tid>>2, 16-col segment
        int rr  = tid >> 2;
        int seg = tid & 3;
        float4 rv = res[rr];
        float g1 = rv.x, g2 = rv.z;
        int   j1 = __float_as_int(rv.y), j2 = __float_as_int(rv.w);
        float* op = out + (size_t)(row0 + rr) * NEXP + seg * 16;
        #pragma unroll
        for (int qq = 0; qq < 4; ++qq) {
            int e0 = seg * 16 + qq * 4;
            float4 o;
            o.x = (e0 + 0 == j1) ? g1 : ((e0 + 0 == j2) ? g2 : 0.f);
            o.y = (e0 + 1 == j1) ? g1 : ((e0 + 1 == j2) ? g2 : 0.f);
            o.z = (e0 + 2 == j1) ? g1 : ((e0 + 2 == j2) ? g2 : 0.f);
            o.w = (e0 + 3 == j1) ? g1 : ((e0 + 3 == j2) ? g2 : 0.f);
            *(float4*)(op + qq * 4) = o;
        }
    }
}

extern "C" void kernel_launch(void* const* d_in, const int* in_sizes, int n_in,
                              void* d_out, int out_size, void* d_ws, size_t ws_size,
                              hipStream_t stream) {
    const float* x     = (const float*)d_in[0];
    const float* wg    = (const float*)d_in[1];
    const float* wn    = (const float*)d_in[2];
    const float* noise = (const float*)d_in[3];
    float* out = (float*)d_out;
    _Float16* wsB = (_Float16*)d_ws;   // needs 64*2*8*1KB = 1 MB

    presplit_kernel<<<dim3(128), 256, 0, stream>>>(wg, wn, wsB);

    const int Brows = in_sizes[0] / DIMK;          // 32768
    dim3 grid(Brows / BM);                         // 512 blocks -> 2/CU
    routing_mfma<<<grid, 256, 0, stream>>>(x, wsB, noise, out);
}